// Round 8
// baseline (46.766 us; speedup 1.0000x reference)
//
#include <hip/hip_runtime.h>
#include <math.h>

#define N  2048
#define K  8
#define NK 1024
#define W  1024          // y-window per block (4 outputs/thread @ 256 threads)
#define TAU_C 0.5f
#define TAU_S 0.5f

// Single fused kernel: no workspace, no producer kernel, no graph-node deps.
// Each block serves output row x, columns [Y0, Y0+W). It rebuilds the needed
// index maps from the immutable input `idx` into LDS:
//   jj_lds[k][y-Y0] = position of y in idx[k] (or -1)
//   ix_lds[k]       = position of x in idx[k] (or -1)
// Every LDS cell has a unique writer (idx[k] values are unique) -> race-free,
// deterministic, replay-safe.
__global__ void __launch_bounds__(256, 4)
fia_fused(const float* __restrict__ adj,
          const int*   __restrict__ idx,
          float* __restrict__ out) {
    __shared__ int jj_lds[K][W];     // 32 KB
    __shared__ int ix_lds[K];

    const int x   = blockIdx.y;                  // output row (uniform)
    const int Y0  = blockIdx.x * W;              // window start
    const int tid = threadIdx.x;

    // ---- init LDS maps to -1
    if (tid < K) ix_lds[tid] = -1;
    {
        int4  m1 = make_int4(-1, -1, -1, -1);
        int4* p4 = (int4*)&jj_lds[0][0];         // K*W/4 = 2048 int4
        #pragma unroll
        for (int q = 0; q < (K * W) / (4 * 256); ++q)
            p4[q * 256 + tid] = m1;
    }
    __syncthreads();

    // ---- scan all (k,p): coalesced reads of idx (32 KB, L1-hot), scatter to LDS
    #pragma unroll
    for (int it = 0; it < (K * NK) / 256; ++it) {
        int t   = it * 256 + tid;                // flat k*NK + p
        int val = idx[t];                        // coalesced
        int k   = t >> 10;                       // uniform within iteration
        int p   = t & (NK - 1);
        int rel = val - Y0;
        if ((unsigned)rel < (unsigned)W) jj_lds[k][rel] = p;
        if (val == x) ix_lds[k] = p;
    }
    __syncthreads();

    // ---- row positions -> wave-uniform SGPRs
    int ix[K];
    #pragma unroll
    for (int k = 0; k < K; ++k)
        ix[k] = __builtin_amdgcn_readfirstlane(ix_lds[k]);

    // ---- column positions: ds_read_b128 per k (4 consecutive ints/thread)
    const int y0 = tid * 4;                      // window-local first column
    int jv[4 * K];
    #pragma unroll
    for (int k = 0; k < K; ++k) {
        int4 v = *(int4*)&jj_lds[k][y0];
        jv[4 * k + 0] = v.x; jv[4 * k + 1] = v.y;
        jv[4 * k + 2] = v.z; jv[4 * k + 3] = v.w;
    }

    // ---- gathers: batched issue, masked later. Consecutive y -> j stride ~1
    // (sorted idx) -> few cache lines per gather instruction.
    float vraw[4][K];
    #pragma unroll
    for (int yy = 0; yy < 4; ++yy)
        #pragma unroll
        for (int k = 0; k < K; ++k) vraw[yy][k] = 0.f;

    int mb[4] = {0, 0, 0, 0};

    #pragma unroll
    for (int k = 0; k < K; ++k) {
        if (ix[k] >= 0) {                        // scalar branch (SGPR cond)
            const float* __restrict__ bk =
                adj + ((size_t)k * NK + (size_t)ix[k]) * NK;
            #pragma unroll
            for (int yy = 0; yy < 4; ++yy) {
                int j  = jv[4 * k + yy];
                int jc = j & ~(j >> 31);         // max(j,0)
                vraw[yy][k] = bk[jc];            // unconditional load
                mb[yy] |= (j >= 0) ? (1 << k) : 0;
            }
        }
    }
    __builtin_amdgcn_sched_barrier(0);           // issue all gathers first

    // ---- stats: byte-for-byte the reference's f32 rounding sequence
    // (R1/R3-R6 proven: absmax 0.0). No fast path (R7 flipped a decision).
    float res[4];
    #pragma unroll
    for (int yy = 0; yy < 4; ++yy) {
        const int m = mb[yy];
        float sum = 0.f;
        #pragma unroll
        for (int k = 0; k < K; ++k) {
            bool p = (m >> k) & 1;
            sum += p ? vraw[yy][k] : 0.f;        // ordered, masked
        }
        float cnt  = (float)__popc(m);
        float n    = fmaxf(cnt, 1e-5f);
        float mean = sum / n;                    // IEEE divide

        float cs = 0.f, vs = 0.f;
        #pragma unroll
        for (int k = 0; k < K; ++k) {
            bool  p = (m >> k) & 1;
            float a = p ? vraw[yy][k] : 0.f;
            cs += (p && (a > TAU_C)) ? 1.f : 0.f;
            float d = a - mean;
            vs += p ? d * d : 0.f;               // select blocks fma-fuse
        }
        float C = cs / n;                        // IEEE divide
        float V = vs / n;                        // IEEE divide
        float S = C * expf(-V);                  // precise expf
        float r = (S > TAU_S) ? mean : 0.f;
        res[yy] = (cnt > 0.f) ? r : 0.f;
    }

    float4 o;
    o.x = res[0]; o.y = res[1]; o.z = res[2]; o.w = res[3];
    *(float4*)(out + (size_t)x * N + Y0 + y0) = o;
}

extern "C" void kernel_launch(void* const* d_in, const int* in_sizes, int n_in,
                              void* d_out, int out_size, void* d_ws, size_t ws_size,
                              hipStream_t stream) {
    const float* adj = (const float*)d_in[0];    // (K, NK, NK) f32
    const int*   idx = (const int*)d_in[1];      // (K, NK) i32
    float*       out = (float*)d_out;            // (N, N) f32

    dim3 block(256, 1, 1);
    dim3 grid(N / W, N, 1);                      // (2, 2048) blocks
    fia_fused<<<grid, block, 0, stream>>>(adj, idx, out);
}

// Round 9
// 29.769 us; speedup vs baseline: 1.5710x; 1.5710x over previous
//
#include <hip/hip_runtime.h>
#include <math.h>

#define N  2048
#define K  8
#define NK 1024
#define R  4             // rows per block (maps reused across rows)
#define TPB 512
#define TAU_C 0.5f
#define TAU_S 0.5f

// Single fused kernel (replay-safe per R8): each block rebuilds index maps from
// the immutable input `idx` into LDS, then serves R=4 full output rows with
// them. jj[k][y] depends only on y and ix[k][x] only on x, so one scan serves
// R*N = 8192 outputs (8x better amortization than R8).
__global__ void __launch_bounds__(TPB, 4)
fia_fused(const float* __restrict__ adj,
          const int*   __restrict__ idx,
          float* __restrict__ out) {
    __shared__ short jj[K][N];       // 32 KB: position of y in idx[k], or -1
    __shared__ short ixs[K][R];      // position of row x in idx[k], or -1

    const int tid = threadIdx.x;
    const int X0  = blockIdx.x * R;

    // ---- init maps to -1 (int4 stores; every cell has a unique scan-writer)
    {
        int4  m1 = make_int4(-1, -1, -1, -1);
        int4* p4 = (int4*)&jj[0][0];                 // K*N*2/16 = 2048 int4
        #pragma unroll
        for (int q = 0; q < (K * N * 2) / (16 * TPB); ++q)   // 4
            p4[q * TPB + tid] = m1;
        if (tid < K * R) ((short*)ixs)[tid] = (short)-1;
    }
    __syncthreads();

    // ---- scan idx (8192 entries, coalesced, L1/L2-hot). val in [0,N) always
    // lands in jj (full-width window). Unique writer per cell -> race-free.
    #pragma unroll
    for (int it = 0; it < (K * NK) / TPB; ++it) {    // 16
        int t   = it * TPB + tid;
        int val = idx[t];                            // coalesced
        int k   = t >> 10;                           // uniform per iteration
        int p   = t & (NK - 1);
        jj[k][val] = (short)p;
        int rel = val - X0;
        if ((unsigned)rel < (unsigned)R) ixs[k][rel] = (short)p;
    }
    __syncthreads();

    // ---- per-thread column state, hoisted out of the row loop (reused R times)
    const int y0 = tid * 4;                          // 4 consecutive columns
    int jc[K][4];                                    // clamped j (element index)
    int jmask[4] = {0, 0, 0, 0};
    #pragma unroll
    for (int k = 0; k < K; ++k) {
        short4 v = *(const short4*)&jj[k][y0];       // ds_read_b64
        int j0 = v.x, j1 = v.y, j2 = v.z, j3 = v.w;
        jmask[0] |= (j0 >= 0) ? (1 << k) : 0;
        jmask[1] |= (j1 >= 0) ? (1 << k) : 0;
        jmask[2] |= (j2 >= 0) ? (1 << k) : 0;
        jmask[3] |= (j3 >= 0) ? (1 << k) : 0;
        jc[k][0] = j0 & ~(j0 >> 31);                 // max(j,0)
        jc[k][1] = j1 & ~(j1 >> 31);
        jc[k][2] = j2 & ~(j2 >> 31);
        jc[k][3] = j3 & ~(j3 >> 31);
    }

    // ---- row loop: per row, only ix changes. #pragma unroll 1 keeps code
    // compact and all register arrays statically indexed (rule #20).
    #pragma unroll 1
    for (int r = 0; r < R; ++r) {
        int kp = 0;
        int ixr[K];
        #pragma unroll
        for (int k = 0; k < K; ++k) {
            int v = (int)ixs[k][r];                  // uniform LDS read
            ixr[k] = __builtin_amdgcn_readfirstlane(v);
            kp |= (ixr[k] >= 0) ? (1 << k) : 0;      // wave-uniform mask
        }

        float vraw[4][K];
        #pragma unroll
        for (int yy = 0; yy < 4; ++yy)
            #pragma unroll
            for (int k = 0; k < K; ++k) vraw[yy][k] = 0.f;

        // gathers: scalar branch per k; batched issue, one drain.
        #pragma unroll
        for (int k = 0; k < K; ++k) {
            if (ixr[k] >= 0) {                       // SGPR condition
                const float* __restrict__ bk =
                    adj + ((size_t)k * NK + (size_t)ixr[k]) * NK;
                #pragma unroll
                for (int yy = 0; yy < 4; ++yy)
                    vraw[yy][k] = bk[jc[k][yy]];     // consecutive-j gather
            }
        }
        __builtin_amdgcn_sched_barrier(0);

        // stats: byte-for-byte the reference's f32 rounding sequence
        // (R1/R3-R6/R8 proven: absmax 0.0). No fast path (R7 lesson).
        float res[4];
        #pragma unroll
        for (int yy = 0; yy < 4; ++yy) {
            const int m = jmask[yy] & kp;
            float sum = 0.f;
            #pragma unroll
            for (int k = 0; k < K; ++k) {
                bool p = (m >> k) & 1;
                sum += p ? vraw[yy][k] : 0.f;        // ordered, masked
            }
            float cnt  = (float)__popc(m);
            float n    = fmaxf(cnt, 1e-5f);
            float mean = sum / n;                    // IEEE divide

            float cs = 0.f, vs = 0.f;
            #pragma unroll
            for (int k = 0; k < K; ++k) {
                bool  p = (m >> k) & 1;
                float a = p ? vraw[yy][k] : 0.f;
                cs += (p && (a > TAU_C)) ? 1.f : 0.f;
                float d = a - mean;
                vs += p ? d * d : 0.f;               // select blocks fma-fuse
            }
            float C = cs / n;                        // IEEE divide
            float V = vs / n;                        // IEEE divide
            float S = C * expf(-V);                  // precise expf
            float rr = (S > TAU_S) ? mean : 0.f;
            res[yy] = (cnt > 0.f) ? rr : 0.f;
        }

        float4 o;
        o.x = res[0]; o.y = res[1]; o.z = res[2]; o.w = res[3];
        *(float4*)(out + (size_t)(X0 + r) * N + y0) = o;
    }
}

extern "C" void kernel_launch(void* const* d_in, const int* in_sizes, int n_in,
                              void* d_out, int out_size, void* d_ws, size_t ws_size,
                              hipStream_t stream) {
    const float* adj = (const float*)d_in[0];        // (K, NK, NK) f32
    const int*   idx = (const int*)d_in[1];          // (K, NK) i32
    float*       out = (float*)d_out;                // (N, N) f32

    dim3 block(TPB, 1, 1);
    dim3 grid(N / R, 1, 1);                          // 512 blocks x 4 rows
    fia_fused<<<grid, block, 0, stream>>>(adj, idx, out);
}